// Round 20
// baseline (487.291 us; speedup 1.0000x reference)
//
#include <hip/hip_runtime.h>

#define N_NODES 100000
#define N_EDGES 3200000
#define NB 782          // dst buckets of 128 nodes: ceil(100000/128)
#define BCAP 5120       // max edges per bucket (avg 4096, 16 sigma guard)
#define CHUNK_EDGES 4096
#define NCHUNKS ((N_EDGES + CHUNK_EDGES - 1) / CHUNK_EDGES)  // 782 (hist granularity)
#define CHUNK_S 32768
#define NCHUNKS_S ((N_EDGES + CHUNK_S - 1) / CHUNK_S)        // 98 (scatter granularity)

typedef unsigned int uint;
typedef __attribute__((ext_vector_type(2))) uint u2v;
typedef __attribute__((ext_vector_type(4))) uint u4v;
typedef __attribute__((ext_vector_type(2))) float f2v;
typedef __attribute__((ext_vector_type(4))) float f4v;
typedef __attribute__((ext_vector_type(8))) short s8v;   // 8 bf16 (4 VGPRs)
typedef __attribute__((ext_vector_type(4))) float f32x4; // mfma acc

// ---------- CSR build: deterministic two-pass bucket partition ----------

__global__ void detect_fmt(const uint* __restrict__ e, int* __restrict__ flag,
                           int* __restrict__ row_ptr) {
    if (threadIdx.x == 0) {
        *flag = (e[1] == 0u && e[3] == 0u && e[5] == 0u && e[7] == 0u) ? 1 : 0;
        row_ptr[N_NODES] = N_EDGES;
    }
}

__device__ __forceinline__ int load_idx(const void* edges, int fmt, long long i) {
    return fmt ? (int)((const long long*)edges)[i] : ((const int*)edges)[i];
}

// hist2 layout: [bucket][chunk] so chunk_scan reads coalesced.
__global__ __launch_bounds__(256) void part_hist(const void* __restrict__ edges,
                                                 const int* __restrict__ flag,
                                                 int* __restrict__ hist2,
                                                 int* __restrict__ bcount) {
    __shared__ int cnt[NB];
    for (int i = threadIdx.x; i < NB; i += 256) cnt[i] = 0;
    __syncthreads();
    int fmt = *flag;
    int c = blockIdx.x;
    int beg = c * CHUNK_EDGES, end = min(beg + CHUNK_EDGES, N_EDGES);
    for (int i = beg + threadIdx.x; i < end; i += 256) {
        int dst = load_idx(edges, fmt, (long long)N_EDGES + i);
        atomicAdd(&cnt[dst >> 7], 1);
    }
    __syncthreads();
    for (int i = threadIdx.x; i < NB; i += 256) {
        hist2[i * NCHUNKS + c] = cnt[i];
        if (cnt[i]) atomicAdd(&bcount[i], cnt[i]);
    }
}

__global__ void scan_kernel(const int* __restrict__ count, int* __restrict__ off_out, int n) {
    __shared__ int sums[1024];
    int t = threadIdx.x;
    int chunk = (n + 1023) >> 10;
    int beg = t * chunk;
    int end = min(beg + chunk, n);
    int s = 0;
    for (int i = beg; i < end; ++i) s += count[i];
    sums[t] = s;
    __syncthreads();
    int val = s;
    for (int off = 1; off < 1024; off <<= 1) {
        int other = (t >= off) ? sums[t - off] : 0;
        __syncthreads();
        val += other;
        sums[t] = val;
        __syncthreads();
    }
    int run = val - s;
    for (int i = beg; i < end; ++i) {
        off_out[i] = run;
        run += count[i];
    }
    if (end >= n) off_out[n] = run;
}

// One block per bucket (1024 threads): exclusive scan over NCHUNKS (782) chunks.
__global__ __launch_bounds__(1024) void chunk_scan(const int* __restrict__ hist2,
                                                   const int* __restrict__ boff,
                                                   int* __restrict__ base2) {
    __shared__ int s[1024];
    int b = blockIdx.x;
    int t = threadIdx.x;
    int v = (t < NCHUNKS) ? hist2[b * NCHUNKS + t] : 0;
    s[t] = v;
    __syncthreads();
    int val = v;
    for (int off = 1; off < 1024; off <<= 1) {
        int o = (t >= off) ? s[t - off] : 0;
        __syncthreads();
        val += o;
        s[t] = val;
        __syncthreads();
    }
    if (t < NCHUNKS) base2[t * NB + b] = boff[b] + val - v;
}

// Scatter in coarse chunks (8 hist chunks each). ~63 us structural floor.
__global__ __launch_bounds__(1024) void part_scatter(const void* __restrict__ edges,
                                                     const int* __restrict__ flag,
                                                     const int* __restrict__ base2,
                                                     uint* __restrict__ tmp) {
    __shared__ int cur[NB];
    int c = blockIdx.x;
    for (int i = threadIdx.x; i < NB; i += 1024) cur[i] = base2[(c * 8) * NB + i];
    __syncthreads();
    int fmt = *flag;
    int beg = c * CHUNK_S, end = min(beg + CHUNK_S, N_EDGES);
    for (int i = beg + (int)threadIdx.x; i < end; i += 1024) {
        int src = load_idx(edges, fmt, i);
        int dst = load_idx(edges, fmt, (long long)N_EDGES + i);
        int b = dst >> 7;
        int pos = atomicAdd(&cur[b], 1);
        tmp[pos] = ((uint)(dst & 127) << 17) | (uint)src;  // src < 2^17
    }
}

__global__ __launch_bounds__(256) void bucket_finalize(const uint* __restrict__ tmp,
                                                       const int* __restrict__ boff,
                                                       int* __restrict__ row_ptr,
                                                       int* __restrict__ esorted) {
    __shared__ uint s1[BCAP];
    __shared__ int s2[BCAP];
    __shared__ int cnt[128], pref[128], cur[128];
    int b = blockIdx.x;
    int beg = boff[b];
    int n = boff[b + 1] - beg;
    if (n > BCAP) n = BCAP;
    int t = threadIdx.x;
    if (t < 128) cnt[t] = 0;
    __syncthreads();
    for (int e = t; e < n; e += 256) {
        uint k = tmp[beg + e];
        s1[e] = k;
        atomicAdd(&cnt[k >> 17], 1);
    }
    __syncthreads();
    if (t < 128) pref[t] = cnt[t];
    __syncthreads();
    for (int off = 1; off < 128; off <<= 1) {
        int v = (t < 128 && t >= off) ? pref[t - off] : 0;
        __syncthreads();
        if (t < 128) pref[t] += v;
        __syncthreads();
    }
    if (t < 128) {
        int ex = pref[t] - cnt[t];
        cur[t] = ex;
        int node = b * 128 + t;
        if (node < N_NODES) row_ptr[node] = beg + ex;
    }
    __syncthreads();
    for (int e = t; e < n; e += 256) {
        uint k = s1[e];
        int p = atomicAdd(&cur[k >> 17], 1);
        s2[p] = (int)(k & 0x1FFFF);
    }
    __syncthreads();
    for (int e = t; e < n; e += 256) esorted[beg + e] = s2[e];
}

// ---------- bf16 helpers ----------

__device__ __forceinline__ uint bf16pack(float a, float b) {
    uint ua = __float_as_uint(a);
    ua = (ua + 0x7FFFu + ((ua >> 16) & 1u)) >> 16;  // RNE
    uint ub = __float_as_uint(b);
    ub = (ub + 0x7FFFu + ((ub >> 16) & 1u)) >> 16;
    return ua | (ub << 16);
}
__device__ __forceinline__ float bf_lo(uint u) { return __uint_as_float(u << 16); }
__device__ __forceinline__ float bf_hi(uint u) { return __uint_as_float(u & 0xFFFF0000u); }

// ---------- linear collapse prep (parallel stages) ----------
// y_{l+1} = (I+A) y_l + 1 c_l with y_0 = h S0, out = y_5.
// S_l = W_l...W_4 ; c_l = b_l^T S_{l+1}.

__global__ __launch_bounds__(256) void matstage(const float* __restrict__ Wl,
                                                const float* __restrict__ bl,
                                                const float* __restrict__ Sin,
                                                float* __restrict__ Sout,
                                                float* __restrict__ cout) {
    __shared__ float S[128 * 64];  // 32 KB
    int tid = threadIdx.x;
    int b = blockIdx.x;
    for (int i = tid; i < 128 * 16; i += 256) ((f4v*)S)[i] = ((const f4v*)Sin)[i];
    __syncthreads();
    if (b < 32) {
        int rr = tid >> 6;
        int c = tid & 63;
        int r = b * 4 + rr;
        const float* wrow = &Wl[r * 128];
        float s = 0.f;
#pragma unroll 8
        for (int k = 0; k < 128; ++k) s += wrow[k] * S[k * 64 + c];
        Sout[r * 64 + c] = s;
    } else if (tid < 64) {
        float s = 0.f;
        for (int k = 0; k < 128; ++k) s += bl[k] * S[k * 64 + tid];
        cout[tid] = s;
    }
}

// Transpose S0 (fp32 [128][64]) -> bf16 [n][c16] u4v, XOR-swizzled; also c4 = b4.
__global__ __launch_bounds__(256) void prep_z(const float* __restrict__ S0,
                                              const float* __restrict__ b4,
                                              u4v* __restrict__ Wt,
                                              float* __restrict__ c_all) {
    int idx = blockIdx.x * 256 + threadIdx.x;  // n*16 + c16, 1024 total
    if (blockIdx.x == 0 && threadIdx.x < 64) c_all[4 * 64 + threadIdx.x] = b4[threadIdx.x];
    if (idx >= 64 * 16) return;
    int n = idx >> 4, c16 = idx & 15;
    u4v o;
#pragma unroll
    for (int q = 0; q < 4; ++q)
        o[q] = bf16pack(S0[(size_t)(c16 * 8 + 2 * q) * 64 + n],
                        S0[(size_t)(c16 * 8 + 2 * q + 1) * 64 + n]);
    Wt[n * 16 + (c16 ^ (n & 7))] = o;
}

// ---------- 64-dim aggregation pass: zn = z + A z + 1 c  (bf16 -> bf16) ----------
// 4 edges/wave-instr (16-lane groups, u2v loads); 8 gathers in flight; esrc via
// nontemporal loads (protect z's L2 residency). 2-level shfl_xor merge.

__global__ __launch_bounds__(256) void agg64_step(const uint* __restrict__ z,
                                                  const int* __restrict__ row_ptr,
                                                  const int* __restrict__ esrc,
                                                  const float* __restrict__ cvec,
                                                  uint* __restrict__ zn) {
    const u2v* z2 = (const u2v*)z;
    int lane = threadIdx.x & 63;
    int c = lane & 15;   // u2v col: dims 4c..4c+3
    int g = lane >> 4;   // edge group 0..3
    int wid = (blockIdx.x * blockDim.x + threadIdx.x) >> 6;
    int nw = (gridDim.x * blockDim.x) >> 6;
    f4v cc = ((const f4v*)cvec)[c];
    for (int v = wid; v < N_NODES; v += nw) {
        f2v aX = {0.f, 0.f}, aY = {0.f, 0.f};
        int beg = row_ptr[v], end = row_ptr[v + 1];
        int i = beg;
        for (; i + 32 <= end; i += 32) {  // 8 x 4 edges, 8 gathers in flight
            uint k[8];
            u2v u[8];
#pragma unroll
            for (int j = 0; j < 8; ++j)
                k[j] = (uint)__builtin_nontemporal_load(&esrc[i + 4 * j + g]);
#pragma unroll
            for (int j = 0; j < 8; ++j) u[j] = z2[k[j] * 16u + (uint)c];
#pragma unroll
            for (int j = 0; j < 8; ++j) {
                f2v t0 = {bf_lo(u[j].x), bf_hi(u[j].x)};
                f2v t1 = {bf_lo(u[j].y), bf_hi(u[j].y)};
                aX += t0;
                aY += t1;
            }
        }
        for (; i + 16 <= end; i += 16) {  // 4 x 4 edges
            uint k[4];
            u2v u[4];
#pragma unroll
            for (int j = 0; j < 4; ++j)
                k[j] = (uint)__builtin_nontemporal_load(&esrc[i + 4 * j + g]);
#pragma unroll
            for (int j = 0; j < 4; ++j) u[j] = z2[k[j] * 16u + (uint)c];
#pragma unroll
            for (int j = 0; j < 4; ++j) {
                f2v t0 = {bf_lo(u[j].x), bf_hi(u[j].x)};
                f2v t1 = {bf_lo(u[j].y), bf_hi(u[j].y)};
                aX += t0;
                aY += t1;
            }
        }
        for (; i < end; i += 4) {
            int idx = i + g;
            u2v uu = {0u, 0u};
            if (idx < end)
                uu = z2[(uint)__builtin_nontemporal_load(&esrc[idx]) * 16u + (uint)c];
            f2v t0 = {bf_lo(uu.x), bf_hi(uu.x)};
            f2v t1 = {bf_lo(uu.y), bf_hi(uu.y)};
            aX += t0;
            aY += t1;
        }
        aX.x += __shfl_xor(aX.x, 16);
        aX.y += __shfl_xor(aX.y, 16);
        aY.x += __shfl_xor(aY.x, 16);
        aY.y += __shfl_xor(aY.y, 16);
        aX.x += __shfl_xor(aX.x, 32);
        aX.y += __shfl_xor(aX.y, 32);
        aY.x += __shfl_xor(aY.x, 32);
        aY.y += __shfl_xor(aY.y, 32);
        if (g == 0) {
            u2v self = z2[(uint)v * 16u + (uint)c];
            u2v o = {bf16pack(aX.x + bf_lo(self.x) + cc.x, aX.y + bf_hi(self.x) + cc.y),
                     bf16pack(aY.x + bf_lo(self.y) + cc.z, aY.y + bf_hi(self.y) + cc.w)};
            __builtin_nontemporal_store(o, &((u2v*)zn)[(uint)v * 16u + (uint)c]);
        }
    }
}

// Final pass: out = z + A z + 1 c4   (fp32 out)
__global__ __launch_bounds__(256) void agg64_last(const uint* __restrict__ z,
                                                  const int* __restrict__ row_ptr,
                                                  const int* __restrict__ esrc,
                                                  const float* __restrict__ cvec,
                                                  float* __restrict__ out) {
    const u2v* z2 = (const u2v*)z;
    int lane = threadIdx.x & 63;
    int c = lane & 15;
    int g = lane >> 4;
    int wid = (blockIdx.x * blockDim.x + threadIdx.x) >> 6;
    int nw = (gridDim.x * blockDim.x) >> 6;
    f4v cc = ((const f4v*)cvec)[c];
    for (int v = wid; v < N_NODES; v += nw) {
        f2v aX = {0.f, 0.f}, aY = {0.f, 0.f};
        int beg = row_ptr[v], end = row_ptr[v + 1];
        int i = beg;
        for (; i + 32 <= end; i += 32) {
            uint k[8];
            u2v u[8];
#pragma unroll
            for (int j = 0; j < 8; ++j)
                k[j] = (uint)__builtin_nontemporal_load(&esrc[i + 4 * j + g]);
#pragma unroll
            for (int j = 0; j < 8; ++j) u[j] = z2[k[j] * 16u + (uint)c];
#pragma unroll
            for (int j = 0; j < 8; ++j) {
                f2v t0 = {bf_lo(u[j].x), bf_hi(u[j].x)};
                f2v t1 = {bf_lo(u[j].y), bf_hi(u[j].y)};
                aX += t0;
                aY += t1;
            }
        }
        for (; i + 16 <= end; i += 16) {
            uint k[4];
            u2v u[4];
#pragma unroll
            for (int j = 0; j < 4; ++j)
                k[j] = (uint)__builtin_nontemporal_load(&esrc[i + 4 * j + g]);
#pragma unroll
            for (int j = 0; j < 4; ++j) u[j] = z2[k[j] * 16u + (uint)c];
#pragma unroll
            for (int j = 0; j < 4; ++j) {
                f2v t0 = {bf_lo(u[j].x), bf_hi(u[j].x)};
                f2v t1 = {bf_lo(u[j].y), bf_hi(u[j].y)};
                aX += t0;
                aY += t1;
            }
        }
        for (; i < end; i += 4) {
            int idx = i + g;
            u2v uu = {0u, 0u};
            if (idx < end)
                uu = z2[(uint)__builtin_nontemporal_load(&esrc[idx]) * 16u + (uint)c];
            f2v t0 = {bf_lo(uu.x), bf_hi(uu.x)};
            f2v t1 = {bf_lo(uu.y), bf_hi(uu.y)};
            aX += t0;
            aY += t1;
        }
        aX.x += __shfl_xor(aX.x, 16);
        aX.y += __shfl_xor(aX.y, 16);
        aY.x += __shfl_xor(aY.x, 16);
        aY.y += __shfl_xor(aY.y, 16);
        aX.x += __shfl_xor(aX.x, 32);
        aX.y += __shfl_xor(aX.y, 32);
        aY.x += __shfl_xor(aY.x, 32);
        aY.y += __shfl_xor(aY.y, 32);
        if (g == 0) {
            u2v self = z2[(uint)v * 16u + (uint)c];
            f4v o = {aX.x + bf_lo(self.x) + cc.x, aX.y + bf_hi(self.x) + cc.y,
                     aY.x + bf_lo(self.y) + cc.z, aY.y + bf_hi(self.y) + cc.w};
            __builtin_nontemporal_store(o, &((f4v*)out)[(uint)v * 16u + (uint)c]);
        }
    }
}

// ---------- MFMA GEMM: z0 = h (fp32 [N][128]) @ S0 -> bf16 [N][64] ----------

__global__ __launch_bounds__(256) void mfma_gemm64(const float* __restrict__ x,
                                                   const u4v* __restrict__ Wt,
                                                   uint* __restrict__ y) {
    constexpr int SMEM = 32768 + 64 * 256;  // A (32K) + B (16K); epilogue reuses A
    __shared__ char raw[SMEM];
    u4v* Asm = (u4v*)raw;                  // [128][16] swizzled
    u4v* Bsm = (u4v*)(raw + 32768);        // [64][16] swizzled
    float* Cst = (float*)raw;              // [128][64] fp32 epilogue overlay (32K)
    int tid = threadIdx.x;
    int m0 = blockIdx.x * 128;

#pragma unroll
    for (int i = 0; i < 8; ++i) {
        int idx = tid + i * 256;
        int r = idx >> 4, c16 = idx & 15;
        int m = m0 + r;
        if (m >= N_NODES) m = N_NODES - 1;
        const float* src = &x[(size_t)m * 128 + c16 * 8];
        f4v v0 = *(const f4v*)src;
        f4v v1 = *(const f4v*)(src + 4);
        u4v o = {bf16pack(v0.x, v0.y), bf16pack(v0.z, v0.w),
                 bf16pack(v1.x, v1.y), bf16pack(v1.z, v1.w)};
        Asm[r * 16 + (c16 ^ (r & 7))] = o;
    }
#pragma unroll
    for (int i = 0; i < 4; ++i) Bsm[tid + i * 256] = Wt[tid + i * 256];
    __syncthreads();

    int lane = tid & 63;
    int w = tid >> 6;
    int n0w = w * 16;
    int lhi = lane >> 4, llo = lane & 15;
    f32x4 acc[8];
#pragma unroll
    for (int i = 0; i < 8; ++i) acc[i] = (f32x4){0.f, 0.f, 0.f, 0.f};

#pragma unroll
    for (int ks = 0; ks < 4; ++ks) {
        int cb = ks * 4 + lhi;
        int col = n0w + llo;
        u4v tb = Bsm[col * 16 + (cb ^ (col & 7))];
        s8v bfr = *(s8v*)&tb;
#pragma unroll
        for (int i = 0; i < 8; ++i) {
            int row = i * 16 + llo;
            u4v t = Asm[row * 16 + (cb ^ (row & 7))];
            s8v aa = *(s8v*)&t;
            acc[i] = __builtin_amdgcn_mfma_f32_16x16x32_bf16(aa, bfr, acc[i], 0, 0, 0);
        }
    }
    __syncthreads();
#pragma unroll
    for (int i = 0; i < 8; ++i)
#pragma unroll
        for (int r = 0; r < 4; ++r)
            Cst[(i * 16 + lhi * 4 + r) * 64 + n0w + llo] = acc[i][r];
    __syncthreads();
#pragma unroll
    for (int i = 0; i < 16; ++i) {
        int idx = tid + i * 256;
        int m = idx >> 5, np = idx & 31;
        if (m0 + m < N_NODES)
            y[(size_t)(m0 + m) * 32 + np] =
                bf16pack(Cst[m * 64 + 2 * np], Cst[m * 64 + 2 * np + 1]);
    }
}

extern "C" void kernel_launch(void* const* d_in, const int* in_sizes, int n_in,
                              void* d_out, int out_size, void* d_ws, size_t ws_size,
                              hipStream_t stream) {
    const float* h_in = (const float*)d_in[0];
    const void* edges = d_in[1];
    const float* W[5] = {(const float*)d_in[2], (const float*)d_in[4], (const float*)d_in[6],
                         (const float*)d_in[8], (const float*)d_in[10]};
    const float* B[5] = {(const float*)d_in[3], (const float*)d_in[5], (const float*)d_in[7],
                         (const float*)d_in[9], (const float*)d_in[11]};

    size_t off = 0;
    auto alloc = [&](size_t bytes) {
        void* p = (char*)d_ws + off;
        off = (off + bytes + 255) & ~(size_t)255;
        return p;
    };
    int* esorted = (int*)alloc((size_t)N_EDGES * 4);            // 12.8 MB
    int* row_ptr = (int*)alloc((size_t)(N_NODES + 1) * 4);
    int* hist2 = (int*)alloc((size_t)NCHUNKS * NB * 4);         // 2.45 MB [b][c]
    int* base2 = (int*)alloc((size_t)NCHUNKS * NB * 4);         // 2.45 MB [c][b]
    int* bcount = (int*)alloc((size_t)NB * 4);
    int* boff = (int*)alloc((size_t)(NB + 1) * 4);
    int* flag = (int*)alloc(256);
    float* Sa = (float*)alloc(128 * 64 * 4);                    // 32 KB ping
    float* Sb = (float*)alloc(128 * 64 * 4);                    // 32 KB pong
    float* c_all = (float*)alloc(5 * 64 * 4);
    u4v* Wt_z = (u4v*)alloc((size_t)64 * 16 * 16);              // 16 KB
    uint* zA = (uint*)alloc((size_t)N_NODES * 32 * 4);          // 12.8 MB
    uint* zB = (uint*)alloc((size_t)N_NODES * 32 * 4);          // 12.8 MB
    uint* tmp = (uint*)alloc((size_t)N_EDGES * 4);              // 12.8 MB (build only)

    // ---- build CSR ----
    detect_fmt<<<1, 64, 0, stream>>>((const uint*)edges, flag, row_ptr);
    (void)hipMemsetAsync(bcount, 0, (size_t)NB * 4, stream);
    part_hist<<<NCHUNKS, 256, 0, stream>>>(edges, flag, hist2, bcount);
    scan_kernel<<<1, 1024, 0, stream>>>(bcount, boff, NB);
    chunk_scan<<<NB, 1024, 0, stream>>>(hist2, boff, base2);
    part_scatter<<<NCHUNKS_S, 1024, 0, stream>>>(edges, flag, base2, tmp);
    bucket_finalize<<<NB, 256, 0, stream>>>(tmp, boff, row_ptr, esorted);

    // ---- collapse prep: S_l chain + c_l = b_l^T S_{l+1} ----
    matstage<<<33, 256, 0, stream>>>(W[3], B[3], W[4], Sa, c_all + 3 * 64);  // S3, c3
    matstage<<<33, 256, 0, stream>>>(W[2], B[2], Sa, Sb, c_all + 2 * 64);    // S2, c2
    matstage<<<33, 256, 0, stream>>>(W[1], B[1], Sb, Sa, c_all + 1 * 64);    // S1, c1
    matstage<<<33, 256, 0, stream>>>(W[0], B[0], Sa, Sb, c_all + 0 * 64);    // S0, c0
    prep_z<<<4, 256, 0, stream>>>(Sb, B[4], Wt_z, c_all);                    // Wt_z, c4

    // ---- z0 = h @ S0; y_{l+1} = (I+A) y_l + c_l (x5, last writes fp32 out) ----
    mfma_gemm64<<<(N_NODES + 127) / 128, 256, 0, stream>>>(h_in, Wt_z, zA);
    agg64_step<<<2048, 256, 0, stream>>>(zA, row_ptr, esorted, c_all + 0 * 64, zB);
    agg64_step<<<2048, 256, 0, stream>>>(zB, row_ptr, esorted, c_all + 1 * 64, zA);
    agg64_step<<<2048, 256, 0, stream>>>(zA, row_ptr, esorted, c_all + 2 * 64, zB);
    agg64_step<<<2048, 256, 0, stream>>>(zB, row_ptr, esorted, c_all + 3 * 64, zA);
    agg64_last<<<2048, 256, 0, stream>>>(zA, row_ptr, esorted, c_all + 4 * 64,
                                         (float*)d_out);
}

// Round 21
// 485.543 us; speedup vs baseline: 1.0036x; 1.0036x over previous
//
#include <hip/hip_runtime.h>

#define N_NODES 100000
#define N_EDGES 3200000
#define NB 782          // dst buckets of 128 nodes: ceil(100000/128)
#define BCAP 5120       // max edges per bucket (avg 4096, 16 sigma guard)
#define CHUNK_EDGES 4096
#define NCHUNKS ((N_EDGES + CHUNK_EDGES - 1) / CHUNK_EDGES)  // 782 (hist granularity)
#define CHUNK_S 32768
#define NCHUNKS_S ((N_EDGES + CHUNK_S - 1) / CHUNK_S)        // 98 (scatter granularity)

typedef unsigned int uint;
typedef __attribute__((ext_vector_type(2))) uint u2v;
typedef __attribute__((ext_vector_type(4))) uint u4v;
typedef __attribute__((ext_vector_type(2))) float f2v;
typedef __attribute__((ext_vector_type(4))) float f4v;
typedef __attribute__((ext_vector_type(8))) short s8v;   // 8 bf16 (4 VGPRs)
typedef __attribute__((ext_vector_type(4))) float f32x4; // mfma acc

// ---------- CSR build: deterministic two-pass bucket partition ----------

__global__ void detect_fmt(const uint* __restrict__ e, int* __restrict__ flag,
                           int* __restrict__ row_ptr) {
    if (threadIdx.x == 0) {
        *flag = (e[1] == 0u && e[3] == 0u && e[5] == 0u && e[7] == 0u) ? 1 : 0;
        row_ptr[N_NODES] = N_EDGES;
    }
}

__device__ __forceinline__ int load_idx(const void* edges, int fmt, long long i) {
    return fmt ? (int)((const long long*)edges)[i] : ((const int*)edges)[i];
}

// hist2 layout: [bucket][chunk] so chunk_scan reads coalesced.
__global__ __launch_bounds__(256) void part_hist(const void* __restrict__ edges,
                                                 const int* __restrict__ flag,
                                                 int* __restrict__ hist2,
                                                 int* __restrict__ bcount) {
    __shared__ int cnt[NB];
    for (int i = threadIdx.x; i < NB; i += 256) cnt[i] = 0;
    __syncthreads();
    int fmt = *flag;
    int c = blockIdx.x;
    int beg = c * CHUNK_EDGES, end = min(beg + CHUNK_EDGES, N_EDGES);
    for (int i = beg + threadIdx.x; i < end; i += 256) {
        int dst = load_idx(edges, fmt, (long long)N_EDGES + i);
        atomicAdd(&cnt[dst >> 7], 1);
    }
    __syncthreads();
    for (int i = threadIdx.x; i < NB; i += 256) {
        hist2[i * NCHUNKS + c] = cnt[i];
        if (cnt[i]) atomicAdd(&bcount[i], cnt[i]);
    }
}

__global__ void scan_kernel(const int* __restrict__ count, int* __restrict__ off_out, int n) {
    __shared__ int sums[1024];
    int t = threadIdx.x;
    int chunk = (n + 1023) >> 10;
    int beg = t * chunk;
    int end = min(beg + chunk, n);
    int s = 0;
    for (int i = beg; i < end; ++i) s += count[i];
    sums[t] = s;
    __syncthreads();
    int val = s;
    for (int off = 1; off < 1024; off <<= 1) {
        int other = (t >= off) ? sums[t - off] : 0;
        __syncthreads();
        val += other;
        sums[t] = val;
        __syncthreads();
    }
    int run = val - s;
    for (int i = beg; i < end; ++i) {
        off_out[i] = run;
        run += count[i];
    }
    if (end >= n) off_out[n] = run;
}

// One block per bucket (1024 threads): exclusive scan over NCHUNKS (782) chunks.
__global__ __launch_bounds__(1024) void chunk_scan(const int* __restrict__ hist2,
                                                   const int* __restrict__ boff,
                                                   int* __restrict__ base2) {
    __shared__ int s[1024];
    int b = blockIdx.x;
    int t = threadIdx.x;
    int v = (t < NCHUNKS) ? hist2[b * NCHUNKS + t] : 0;
    s[t] = v;
    __syncthreads();
    int val = v;
    for (int off = 1; off < 1024; off <<= 1) {
        int o = (t >= off) ? s[t - off] : 0;
        __syncthreads();
        val += o;
        s[t] = val;
        __syncthreads();
    }
    if (t < NCHUNKS) base2[t * NB + b] = boff[b] + val - v;
}

// Scatter in coarse chunks (8 hist chunks each). ~63 us structural floor.
__global__ __launch_bounds__(1024) void part_scatter(const void* __restrict__ edges,
                                                     const int* __restrict__ flag,
                                                     const int* __restrict__ base2,
                                                     uint* __restrict__ tmp) {
    __shared__ int cur[NB];
    int c = blockIdx.x;
    for (int i = threadIdx.x; i < NB; i += 1024) cur[i] = base2[(c * 8) * NB + i];
    __syncthreads();
    int fmt = *flag;
    int beg = c * CHUNK_S, end = min(beg + CHUNK_S, N_EDGES);
    for (int i = beg + (int)threadIdx.x; i < end; i += 1024) {
        int src = load_idx(edges, fmt, i);
        int dst = load_idx(edges, fmt, (long long)N_EDGES + i);
        int b = dst >> 7;
        int pos = atomicAdd(&cur[b], 1);
        tmp[pos] = ((uint)(dst & 127) << 17) | (uint)src;  // src < 2^17
    }
}

__global__ __launch_bounds__(256) void bucket_finalize(const uint* __restrict__ tmp,
                                                       const int* __restrict__ boff,
                                                       int* __restrict__ row_ptr,
                                                       int* __restrict__ esorted) {
    __shared__ uint s1[BCAP];
    __shared__ int s2[BCAP];
    __shared__ int cnt[128], pref[128], cur[128];
    int b = blockIdx.x;
    int beg = boff[b];
    int n = boff[b + 1] - beg;
    if (n > BCAP) n = BCAP;
    int t = threadIdx.x;
    if (t < 128) cnt[t] = 0;
    __syncthreads();
    for (int e = t; e < n; e += 256) {
        uint k = tmp[beg + e];
        s1[e] = k;
        atomicAdd(&cnt[k >> 17], 1);
    }
    __syncthreads();
    if (t < 128) pref[t] = cnt[t];
    __syncthreads();
    for (int off = 1; off < 128; off <<= 1) {
        int v = (t < 128 && t >= off) ? pref[t - off] : 0;
        __syncthreads();
        if (t < 128) pref[t] += v;
        __syncthreads();
    }
    if (t < 128) {
        int ex = pref[t] - cnt[t];
        cur[t] = ex;
        int node = b * 128 + t;
        if (node < N_NODES) row_ptr[node] = beg + ex;
    }
    __syncthreads();
    for (int e = t; e < n; e += 256) {
        uint k = s1[e];
        int p = atomicAdd(&cur[k >> 17], 1);
        s2[p] = (int)(k & 0x1FFFF);
    }
    __syncthreads();
    for (int e = t; e < n; e += 256) esorted[beg + e] = s2[e];
}

// ---------- bf16 helpers ----------

__device__ __forceinline__ uint bf16pack(float a, float b) {
    uint ua = __float_as_uint(a);
    ua = (ua + 0x7FFFu + ((ua >> 16) & 1u)) >> 16;  // RNE
    uint ub = __float_as_uint(b);
    ub = (ub + 0x7FFFu + ((ub >> 16) & 1u)) >> 16;
    return ua | (ub << 16);
}
__device__ __forceinline__ float bf_lo(uint u) { return __uint_as_float(u << 16); }
__device__ __forceinline__ float bf_hi(uint u) { return __uint_as_float(u & 0xFFFF0000u); }

// ---------- linear collapse prep (parallel stages) ----------
// y_{l+1} = (I+A) y_l + 1 c_l with y_0 = h S0, out = y_5.
// S_l = W_l...W_4 ; c_l = b_l^T S_{l+1}.

__global__ __launch_bounds__(256) void matstage(const float* __restrict__ Wl,
                                                const float* __restrict__ bl,
                                                const float* __restrict__ Sin,
                                                float* __restrict__ Sout,
                                                float* __restrict__ cout) {
    __shared__ float S[128 * 64];  // 32 KB
    int tid = threadIdx.x;
    int b = blockIdx.x;
    for (int i = tid; i < 128 * 16; i += 256) ((f4v*)S)[i] = ((const f4v*)Sin)[i];
    __syncthreads();
    if (b < 32) {
        int rr = tid >> 6;
        int c = tid & 63;
        int r = b * 4 + rr;
        const float* wrow = &Wl[r * 128];
        float s = 0.f;
#pragma unroll 8
        for (int k = 0; k < 128; ++k) s += wrow[k] * S[k * 64 + c];
        Sout[r * 64 + c] = s;
    } else if (tid < 64) {
        float s = 0.f;
        for (int k = 0; k < 128; ++k) s += bl[k] * S[k * 64 + tid];
        cout[tid] = s;
    }
}

// Transpose S0 (fp32 [128][64]) -> bf16 [n][c16] u4v, XOR-swizzled; also c4 = b4.
__global__ __launch_bounds__(256) void prep_z(const float* __restrict__ S0,
                                              const float* __restrict__ b4,
                                              u4v* __restrict__ Wt,
                                              float* __restrict__ c_all) {
    int idx = blockIdx.x * 256 + threadIdx.x;  // n*16 + c16, 1024 total
    if (blockIdx.x == 0 && threadIdx.x < 64) c_all[4 * 64 + threadIdx.x] = b4[threadIdx.x];
    if (idx >= 64 * 16) return;
    int n = idx >> 4, c16 = idx & 15;
    u4v o;
#pragma unroll
    for (int q = 0; q < 4; ++q)
        o[q] = bf16pack(S0[(size_t)(c16 * 8 + 2 * q) * 64 + n],
                        S0[(size_t)(c16 * 8 + 2 * q + 1) * 64 + n]);
    Wt[n * 16 + (c16 ^ (n & 7))] = o;
}

// ---------- 64-dim aggregation pass: zn = z + A z + 1 c  (bf16 -> bf16) ----------
// 4 edges/wave-instr (16-lane groups, u2v loads); 8 gathers in flight; esrc via
// nontemporal loads (protect z's L2 residency). 2-level shfl_xor merge.

__global__ __launch_bounds__(256) void agg64_step(const uint* __restrict__ z,
                                                  const int* __restrict__ row_ptr,
                                                  const int* __restrict__ esrc,
                                                  const float* __restrict__ cvec,
                                                  uint* __restrict__ zn) {
    const u2v* z2 = (const u2v*)z;
    int lane = threadIdx.x & 63;
    int c = lane & 15;   // u2v col: dims 4c..4c+3
    int g = lane >> 4;   // edge group 0..3
    int wid = (blockIdx.x * blockDim.x + threadIdx.x) >> 6;
    int nw = (gridDim.x * blockDim.x) >> 6;
    f4v cc = ((const f4v*)cvec)[c];
    for (int v = wid; v < N_NODES; v += nw) {
        f2v aX = {0.f, 0.f}, aY = {0.f, 0.f};
        int beg = row_ptr[v], end = row_ptr[v + 1];
        int i = beg;
        for (; i + 32 <= end; i += 32) {  // 8 x 4 edges, 8 gathers in flight
            uint k[8];
            u2v u[8];
#pragma unroll
            for (int j = 0; j < 8; ++j)
                k[j] = (uint)__builtin_nontemporal_load(&esrc[i + 4 * j + g]);
#pragma unroll
            for (int j = 0; j < 8; ++j) u[j] = z2[k[j] * 16u + (uint)c];
#pragma unroll
            for (int j = 0; j < 8; ++j) {
                f2v t0 = {bf_lo(u[j].x), bf_hi(u[j].x)};
                f2v t1 = {bf_lo(u[j].y), bf_hi(u[j].y)};
                aX += t0;
                aY += t1;
            }
        }
        for (; i + 16 <= end; i += 16) {  // 4 x 4 edges
            uint k[4];
            u2v u[4];
#pragma unroll
            for (int j = 0; j < 4; ++j)
                k[j] = (uint)__builtin_nontemporal_load(&esrc[i + 4 * j + g]);
#pragma unroll
            for (int j = 0; j < 4; ++j) u[j] = z2[k[j] * 16u + (uint)c];
#pragma unroll
            for (int j = 0; j < 4; ++j) {
                f2v t0 = {bf_lo(u[j].x), bf_hi(u[j].x)};
                f2v t1 = {bf_lo(u[j].y), bf_hi(u[j].y)};
                aX += t0;
                aY += t1;
            }
        }
        for (; i < end; i += 4) {
            int idx = i + g;
            u2v uu = {0u, 0u};
            if (idx < end)
                uu = z2[(uint)__builtin_nontemporal_load(&esrc[idx]) * 16u + (uint)c];
            f2v t0 = {bf_lo(uu.x), bf_hi(uu.x)};
            f2v t1 = {bf_lo(uu.y), bf_hi(uu.y)};
            aX += t0;
            aY += t1;
        }
        aX.x += __shfl_xor(aX.x, 16);
        aX.y += __shfl_xor(aX.y, 16);
        aY.x += __shfl_xor(aY.x, 16);
        aY.y += __shfl_xor(aY.y, 16);
        aX.x += __shfl_xor(aX.x, 32);
        aX.y += __shfl_xor(aX.y, 32);
        aY.x += __shfl_xor(aY.x, 32);
        aY.y += __shfl_xor(aY.y, 32);
        if (g == 0) {
            u2v self = z2[(uint)v * 16u + (uint)c];
            u2v o = {bf16pack(aX.x + bf_lo(self.x) + cc.x, aX.y + bf_hi(self.x) + cc.y),
                     bf16pack(aY.x + bf_lo(self.y) + cc.z, aY.y + bf_hi(self.y) + cc.w)};
            __builtin_nontemporal_store(o, &((u2v*)zn)[(uint)v * 16u + (uint)c]);
        }
    }
}

// Final pass: out = z + A z + 1 c4   (fp32 out)
__global__ __launch_bounds__(256) void agg64_last(const uint* __restrict__ z,
                                                  const int* __restrict__ row_ptr,
                                                  const int* __restrict__ esrc,
                                                  const float* __restrict__ cvec,
                                                  float* __restrict__ out) {
    const u2v* z2 = (const u2v*)z;
    int lane = threadIdx.x & 63;
    int c = lane & 15;
    int g = lane >> 4;
    int wid = (blockIdx.x * blockDim.x + threadIdx.x) >> 6;
    int nw = (gridDim.x * blockDim.x) >> 6;
    f4v cc = ((const f4v*)cvec)[c];
    for (int v = wid; v < N_NODES; v += nw) {
        f2v aX = {0.f, 0.f}, aY = {0.f, 0.f};
        int beg = row_ptr[v], end = row_ptr[v + 1];
        int i = beg;
        for (; i + 32 <= end; i += 32) {
            uint k[8];
            u2v u[8];
#pragma unroll
            for (int j = 0; j < 8; ++j)
                k[j] = (uint)__builtin_nontemporal_load(&esrc[i + 4 * j + g]);
#pragma unroll
            for (int j = 0; j < 8; ++j) u[j] = z2[k[j] * 16u + (uint)c];
#pragma unroll
            for (int j = 0; j < 8; ++j) {
                f2v t0 = {bf_lo(u[j].x), bf_hi(u[j].x)};
                f2v t1 = {bf_lo(u[j].y), bf_hi(u[j].y)};
                aX += t0;
                aY += t1;
            }
        }
        for (; i + 16 <= end; i += 16) {
            uint k[4];
            u2v u[4];
#pragma unroll
            for (int j = 0; j < 4; ++j)
                k[j] = (uint)__builtin_nontemporal_load(&esrc[i + 4 * j + g]);
#pragma unroll
            for (int j = 0; j < 4; ++j) u[j] = z2[k[j] * 16u + (uint)c];
#pragma unroll
            for (int j = 0; j < 4; ++j) {
                f2v t0 = {bf_lo(u[j].x), bf_hi(u[j].x)};
                f2v t1 = {bf_lo(u[j].y), bf_hi(u[j].y)};
                aX += t0;
                aY += t1;
            }
        }
        for (; i < end; i += 4) {
            int idx = i + g;
            u2v uu = {0u, 0u};
            if (idx < end)
                uu = z2[(uint)__builtin_nontemporal_load(&esrc[idx]) * 16u + (uint)c];
            f2v t0 = {bf_lo(uu.x), bf_hi(uu.x)};
            f2v t1 = {bf_lo(uu.y), bf_hi(uu.y)};
            aX += t0;
            aY += t1;
        }
        aX.x += __shfl_xor(aX.x, 16);
        aX.y += __shfl_xor(aX.y, 16);
        aY.x += __shfl_xor(aY.x, 16);
        aY.y += __shfl_xor(aY.y, 16);
        aX.x += __shfl_xor(aX.x, 32);
        aX.y += __shfl_xor(aX.y, 32);
        aY.x += __shfl_xor(aY.x, 32);
        aY.y += __shfl_xor(aY.y, 32);
        if (g == 0) {
            u2v self = z2[(uint)v * 16u + (uint)c];
            f4v o = {aX.x + bf_lo(self.x) + cc.x, aX.y + bf_hi(self.x) + cc.y,
                     aY.x + bf_lo(self.y) + cc.z, aY.y + bf_hi(self.y) + cc.w};
            __builtin_nontemporal_store(o, &((f4v*)out)[(uint)v * 16u + (uint)c]);
        }
    }
}

// ---------- MFMA GEMM: z0 = h (fp32 [N][128]) @ S0 -> bf16 [N][64] ----------

__global__ __launch_bounds__(256) void mfma_gemm64(const float* __restrict__ x,
                                                   const u4v* __restrict__ Wt,
                                                   uint* __restrict__ y) {
    constexpr int SMEM = 32768 + 64 * 256;  // A (32K) + B (16K); epilogue reuses A
    __shared__ char raw[SMEM];
    u4v* Asm = (u4v*)raw;                  // [128][16] swizzled
    u4v* Bsm = (u4v*)(raw + 32768);        // [64][16] swizzled
    float* Cst = (float*)raw;              // [128][64] fp32 epilogue overlay (32K)
    int tid = threadIdx.x;
    int m0 = blockIdx.x * 128;

#pragma unroll
    for (int i = 0; i < 8; ++i) {
        int idx = tid + i * 256;
        int r = idx >> 4, c16 = idx & 15;
        int m = m0 + r;
        if (m >= N_NODES) m = N_NODES - 1;
        const float* src = &x[(size_t)m * 128 + c16 * 8];
        f4v v0 = *(const f4v*)src;
        f4v v1 = *(const f4v*)(src + 4);
        u4v o = {bf16pack(v0.x, v0.y), bf16pack(v0.z, v0.w),
                 bf16pack(v1.x, v1.y), bf16pack(v1.z, v1.w)};
        Asm[r * 16 + (c16 ^ (r & 7))] = o;
    }
#pragma unroll
    for (int i = 0; i < 4; ++i) Bsm[tid + i * 256] = Wt[tid + i * 256];
    __syncthreads();

    int lane = tid & 63;
    int w = tid >> 6;
    int n0w = w * 16;
    int lhi = lane >> 4, llo = lane & 15;
    f32x4 acc[8];
#pragma unroll
    for (int i = 0; i < 8; ++i) acc[i] = (f32x4){0.f, 0.f, 0.f, 0.f};

#pragma unroll
    for (int ks = 0; ks < 4; ++ks) {
        int cb = ks * 4 + lhi;
        int col = n0w + llo;
        u4v tb = Bsm[col * 16 + (cb ^ (col & 7))];
        s8v bfr = *(s8v*)&tb;
#pragma unroll
        for (int i = 0; i < 8; ++i) {
            int row = i * 16 + llo;
            u4v t = Asm[row * 16 + (cb ^ (row & 7))];
            s8v aa = *(s8v*)&t;
            acc[i] = __builtin_amdgcn_mfma_f32_16x16x32_bf16(aa, bfr, acc[i], 0, 0, 0);
        }
    }
    __syncthreads();
#pragma unroll
    for (int i = 0; i < 8; ++i)
#pragma unroll
        for (int r = 0; r < 4; ++r)
            Cst[(i * 16 + lhi * 4 + r) * 64 + n0w + llo] = acc[i][r];
    __syncthreads();
#pragma unroll
    for (int i = 0; i < 16; ++i) {
        int idx = tid + i * 256;
        int m = idx >> 5, np = idx & 31;
        if (m0 + m < N_NODES)
            y[(size_t)(m0 + m) * 32 + np] =
                bf16pack(Cst[m * 64 + 2 * np], Cst[m * 64 + 2 * np + 1]);
    }
}

extern "C" void kernel_launch(void* const* d_in, const int* in_sizes, int n_in,
                              void* d_out, int out_size, void* d_ws, size_t ws_size,
                              hipStream_t stream) {
    const float* h_in = (const float*)d_in[0];
    const void* edges = d_in[1];
    const float* W[5] = {(const float*)d_in[2], (const float*)d_in[4], (const float*)d_in[6],
                         (const float*)d_in[8], (const float*)d_in[10]};
    const float* B[5] = {(const float*)d_in[3], (const float*)d_in[5], (const float*)d_in[7],
                         (const float*)d_in[9], (const float*)d_in[11]};

    size_t off = 0;
    auto alloc = [&](size_t bytes) {
        void* p = (char*)d_ws + off;
        off = (off + bytes + 255) & ~(size_t)255;
        return p;
    };
    int* esorted = (int*)alloc((size_t)N_EDGES * 4);            // 12.8 MB
    int* row_ptr = (int*)alloc((size_t)(N_NODES + 1) * 4);
    int* hist2 = (int*)alloc((size_t)NCHUNKS * NB * 4);         // 2.45 MB [b][c]
    int* base2 = (int*)alloc((size_t)NCHUNKS * NB * 4);         // 2.45 MB [c][b]
    int* bcount = (int*)alloc((size_t)NB * 4);
    int* boff = (int*)alloc((size_t)(NB + 1) * 4);
    int* flag = (int*)alloc(256);
    float* Sa = (float*)alloc(128 * 64 * 4);                    // 32 KB ping
    float* Sb = (float*)alloc(128 * 64 * 4);                    // 32 KB pong
    float* c_all = (float*)alloc(5 * 64 * 4);
    u4v* Wt_z = (u4v*)alloc((size_t)64 * 16 * 16);              // 16 KB
    uint* zA = (uint*)alloc((size_t)N_NODES * 32 * 4);          // 12.8 MB
    uint* zB = (uint*)alloc((size_t)N_NODES * 32 * 4);          // 12.8 MB
    uint* tmp = (uint*)alloc((size_t)N_EDGES * 4);              // 12.8 MB (build only)

    // ---- build CSR ----
    detect_fmt<<<1, 64, 0, stream>>>((const uint*)edges, flag, row_ptr);
    (void)hipMemsetAsync(bcount, 0, (size_t)NB * 4, stream);
    part_hist<<<NCHUNKS, 256, 0, stream>>>(edges, flag, hist2, bcount);
    scan_kernel<<<1, 1024, 0, stream>>>(bcount, boff, NB);
    chunk_scan<<<NB, 1024, 0, stream>>>(hist2, boff, base2);
    part_scatter<<<NCHUNKS_S, 1024, 0, stream>>>(edges, flag, base2, tmp);
    bucket_finalize<<<NB, 256, 0, stream>>>(tmp, boff, row_ptr, esorted);

    // ---- collapse prep: S_l chain + c_l = b_l^T S_{l+1} ----
    matstage<<<33, 256, 0, stream>>>(W[3], B[3], W[4], Sa, c_all + 3 * 64);  // S3, c3
    matstage<<<33, 256, 0, stream>>>(W[2], B[2], Sa, Sb, c_all + 2 * 64);    // S2, c2
    matstage<<<33, 256, 0, stream>>>(W[1], B[1], Sb, Sa, c_all + 1 * 64);    // S1, c1
    matstage<<<33, 256, 0, stream>>>(W[0], B[0], Sa, Sb, c_all + 0 * 64);    // S0, c0
    prep_z<<<4, 256, 0, stream>>>(Sb, B[4], Wt_z, c_all);                    // Wt_z, c4

    // ---- z0 = h @ S0; y_{l+1} = (I+A) y_l + c_l (x5, last writes fp32 out) ----
    mfma_gemm64<<<(N_NODES + 127) / 128, 256, 0, stream>>>(h_in, Wt_z, zA);
    agg64_step<<<2048, 256, 0, stream>>>(zA, row_ptr, esorted, c_all + 0 * 64, zB);
    agg64_step<<<2048, 256, 0, stream>>>(zB, row_ptr, esorted, c_all + 1 * 64, zA);
    agg64_step<<<2048, 256, 0, stream>>>(zA, row_ptr, esorted, c_all + 2 * 64, zB);
    agg64_step<<<2048, 256, 0, stream>>>(zB, row_ptr, esorted, c_all + 3 * 64, zA);
    agg64_last<<<2048, 256, 0, stream>>>(zA, row_ptr, esorted, c_all + 4 * 64,
                                         (float*)d_out);
}

// Round 22
// 423.066 us; speedup vs baseline: 1.1518x; 1.1477x over previous
//
#include <hip/hip_runtime.h>

#define N_NODES 100000
#define N_EDGES 3200000
#define NB 782          // dst buckets of 128 nodes: ceil(100000/128)
#define BCAP 5120       // max edges per bucket (avg 4096, 16 sigma guard)
#define CHUNK_EDGES 4096
#define NCHUNKS ((N_EDGES + CHUNK_EDGES - 1) / CHUNK_EDGES)  // 782 (hist granularity)
#define CHUNK_S 32768
#define NCHUNKS_S ((N_EDGES + CHUNK_S - 1) / CHUNK_S)        // 98 (scatter granularity)

typedef unsigned int uint;
typedef __attribute__((ext_vector_type(2))) uint u2v;
typedef __attribute__((ext_vector_type(4))) uint u4v;
typedef __attribute__((ext_vector_type(2))) float f2v;
typedef __attribute__((ext_vector_type(4))) float f4v;
typedef __attribute__((ext_vector_type(8))) short s8v;   // 8 bf16 (4 VGPRs)
typedef __attribute__((ext_vector_type(4))) float f32x4; // mfma acc

// ---------- CSR build: deterministic two-pass bucket partition ----------

__global__ void detect_fmt(const uint* __restrict__ e, int* __restrict__ flag,
                           int* __restrict__ row_ptr) {
    if (threadIdx.x == 0) {
        *flag = (e[1] == 0u && e[3] == 0u && e[5] == 0u && e[7] == 0u) ? 1 : 0;
        row_ptr[N_NODES] = N_EDGES;
    }
}

__device__ __forceinline__ int load_idx(const void* edges, int fmt, long long i) {
    return fmt ? (int)((const long long*)edges)[i] : ((const int*)edges)[i];
}

// hist2 layout: [bucket][chunk] so chunk_scan reads coalesced.
__global__ __launch_bounds__(256) void part_hist(const void* __restrict__ edges,
                                                 const int* __restrict__ flag,
                                                 int* __restrict__ hist2,
                                                 int* __restrict__ bcount) {
    __shared__ int cnt[NB];
    for (int i = threadIdx.x; i < NB; i += 256) cnt[i] = 0;
    __syncthreads();
    int fmt = *flag;
    int c = blockIdx.x;
    int beg = c * CHUNK_EDGES, end = min(beg + CHUNK_EDGES, N_EDGES);
    for (int i = beg + threadIdx.x; i < end; i += 256) {
        int dst = load_idx(edges, fmt, (long long)N_EDGES + i);
        atomicAdd(&cnt[dst >> 7], 1);
    }
    __syncthreads();
    for (int i = threadIdx.x; i < NB; i += 256) {
        hist2[i * NCHUNKS + c] = cnt[i];
        if (cnt[i]) atomicAdd(&bcount[i], cnt[i]);
    }
}

__global__ void scan_kernel(const int* __restrict__ count, int* __restrict__ off_out, int n) {
    __shared__ int sums[1024];
    int t = threadIdx.x;
    int chunk = (n + 1023) >> 10;
    int beg = t * chunk;
    int end = min(beg + chunk, n);
    int s = 0;
    for (int i = beg; i < end; ++i) s += count[i];
    sums[t] = s;
    __syncthreads();
    int val = s;
    for (int off = 1; off < 1024; off <<= 1) {
        int other = (t >= off) ? sums[t - off] : 0;
        __syncthreads();
        val += other;
        sums[t] = val;
        __syncthreads();
    }
    int run = val - s;
    for (int i = beg; i < end; ++i) {
        off_out[i] = run;
        run += count[i];
    }
    if (end >= n) off_out[n] = run;
}

// One block per bucket (1024 threads): exclusive scan over NCHUNKS (782) chunks.
__global__ __launch_bounds__(1024) void chunk_scan(const int* __restrict__ hist2,
                                                   const int* __restrict__ boff,
                                                   int* __restrict__ base2) {
    __shared__ int s[1024];
    int b = blockIdx.x;
    int t = threadIdx.x;
    int v = (t < NCHUNKS) ? hist2[b * NCHUNKS + t] : 0;
    s[t] = v;
    __syncthreads();
    int val = v;
    for (int off = 1; off < 1024; off <<= 1) {
        int o = (t >= off) ? s[t - off] : 0;
        __syncthreads();
        val += o;
        s[t] = val;
        __syncthreads();
    }
    if (t < NCHUNKS) base2[t * NB + b] = boff[b] + val - v;
}

// Scatter in coarse chunks (8 hist chunks each). ~63 us structural floor.
__global__ __launch_bounds__(1024) void part_scatter(const void* __restrict__ edges,
                                                     const int* __restrict__ flag,
                                                     const int* __restrict__ base2,
                                                     uint* __restrict__ tmp) {
    __shared__ int cur[NB];
    int c = blockIdx.x;
    for (int i = threadIdx.x; i < NB; i += 1024) cur[i] = base2[(c * 8) * NB + i];
    __syncthreads();
    int fmt = *flag;
    int beg = c * CHUNK_S, end = min(beg + CHUNK_S, N_EDGES);
    for (int i = beg + (int)threadIdx.x; i < end; i += 1024) {
        int src = load_idx(edges, fmt, i);
        int dst = load_idx(edges, fmt, (long long)N_EDGES + i);
        int b = dst >> 7;
        int pos = atomicAdd(&cur[b], 1);
        tmp[pos] = ((uint)(dst & 127) << 17) | (uint)src;  // src < 2^17
    }
}

__global__ __launch_bounds__(256) void bucket_finalize(const uint* __restrict__ tmp,
                                                       const int* __restrict__ boff,
                                                       int* __restrict__ row_ptr,
                                                       int* __restrict__ esorted) {
    __shared__ uint s1[BCAP];
    __shared__ int s2[BCAP];
    __shared__ int cnt[128], pref[128], cur[128];
    int b = blockIdx.x;
    int beg = boff[b];
    int n = boff[b + 1] - beg;
    if (n > BCAP) n = BCAP;
    int t = threadIdx.x;
    if (t < 128) cnt[t] = 0;
    __syncthreads();
    for (int e = t; e < n; e += 256) {
        uint k = tmp[beg + e];
        s1[e] = k;
        atomicAdd(&cnt[k >> 17], 1);
    }
    __syncthreads();
    if (t < 128) pref[t] = cnt[t];
    __syncthreads();
    for (int off = 1; off < 128; off <<= 1) {
        int v = (t < 128 && t >= off) ? pref[t - off] : 0;
        __syncthreads();
        if (t < 128) pref[t] += v;
        __syncthreads();
    }
    if (t < 128) {
        int ex = pref[t] - cnt[t];
        cur[t] = ex;
        int node = b * 128 + t;
        if (node < N_NODES) row_ptr[node] = beg + ex;
    }
    __syncthreads();
    for (int e = t; e < n; e += 256) {
        uint k = s1[e];
        int p = atomicAdd(&cur[k >> 17], 1);
        s2[p] = (int)(k & 0x1FFFF);
    }
    __syncthreads();
    for (int e = t; e < n; e += 256) esorted[beg + e] = s2[e];
}

// ---------- bf16 helpers ----------

__device__ __forceinline__ uint bf16pack(float a, float b) {
    uint ua = __float_as_uint(a);
    ua = (ua + 0x7FFFu + ((ua >> 16) & 1u)) >> 16;  // RNE
    uint ub = __float_as_uint(b);
    ub = (ub + 0x7FFFu + ((ub >> 16) & 1u)) >> 16;
    return ua | (ub << 16);
}
__device__ __forceinline__ float bf_lo(uint u) { return __uint_as_float(u << 16); }
__device__ __forceinline__ float bf_hi(uint u) { return __uint_as_float(u & 0xFFFF0000u); }

// ---------- linear collapse prep (parallel stages) ----------
// y_{l+1} = (I+A) y_l + 1 c_l with y_0 = h S0, out = y_5.
// S_l = W_l...W_4 ; c_l = b_l^T S_{l+1}.

__global__ __launch_bounds__(256) void matstage(const float* __restrict__ Wl,
                                                const float* __restrict__ bl,
                                                const float* __restrict__ Sin,
                                                float* __restrict__ Sout,
                                                float* __restrict__ cout) {
    __shared__ float S[128 * 64];  // 32 KB
    int tid = threadIdx.x;
    int b = blockIdx.x;
    for (int i = tid; i < 128 * 16; i += 256) ((f4v*)S)[i] = ((const f4v*)Sin)[i];
    __syncthreads();
    if (b < 32) {
        int rr = tid >> 6;
        int c = tid & 63;
        int r = b * 4 + rr;
        const float* wrow = &Wl[r * 128];
        float s = 0.f;
#pragma unroll 8
        for (int k = 0; k < 128; ++k) s += wrow[k] * S[k * 64 + c];
        Sout[r * 64 + c] = s;
    } else if (tid < 64) {
        float s = 0.f;
        for (int k = 0; k < 128; ++k) s += bl[k] * S[k * 64 + tid];
        cout[tid] = s;
    }
}

// Transpose S0 (fp32 [128][64]) -> bf16 [n][c16] u4v, XOR-swizzled; also c4 = b4.
__global__ __launch_bounds__(256) void prep_z(const float* __restrict__ S0,
                                              const float* __restrict__ b4,
                                              u4v* __restrict__ Wt,
                                              float* __restrict__ c_all) {
    int idx = blockIdx.x * 256 + threadIdx.x;  // n*16 + c16, 1024 total
    if (blockIdx.x == 0 && threadIdx.x < 64) c_all[4 * 64 + threadIdx.x] = b4[threadIdx.x];
    if (idx >= 64 * 16) return;
    int n = idx >> 4, c16 = idx & 15;
    u4v o;
#pragma unroll
    for (int q = 0; q < 4; ++q)
        o[q] = bf16pack(S0[(size_t)(c16 * 8 + 2 * q) * 64 + n],
                        S0[(size_t)(c16 * 8 + 2 * q + 1) * 64 + n]);
    Wt[n * 16 + (c16 ^ (n & 7))] = o;
}

// ---------- 64-dim aggregation pass: zn = z + A z + 1 c  (bf16 -> bf16) ----------
// 8 edges/wave-instr: 8-lane groups, lane loads u4v (16B) -> one
// global_load_dwordx4 covers 8 full 128B rows. Plain esrc loads (nt hurt: R21).
// 3-level shfl_xor merge over 8 accumulators.

__global__ __launch_bounds__(256) void agg64_step(const uint* __restrict__ z,
                                                  const int* __restrict__ row_ptr,
                                                  const int* __restrict__ esrc,
                                                  const float* __restrict__ cvec,
                                                  uint* __restrict__ zn) {
    const u4v* z4 = (const u4v*)z;
    int lane = threadIdx.x & 63;
    int c = lane & 7;    // u4v col: dims 8c..8c+7
    int g = lane >> 3;   // edge group 0..7
    int wid = (blockIdx.x * blockDim.x + threadIdx.x) >> 6;
    int nw = (gridDim.x * blockDim.x) >> 6;
    f4v cc0 = ((const f4v*)cvec)[2 * c];
    f4v cc1 = ((const f4v*)cvec)[2 * c + 1];
    for (int v = wid; v < N_NODES; v += nw) {
        f2v a0 = {0.f, 0.f}, a1 = {0.f, 0.f}, a2 = {0.f, 0.f}, a3 = {0.f, 0.f};
        int beg = row_ptr[v], end = row_ptr[v + 1];
        int i = beg;
        for (; i + 32 <= end; i += 32) {  // 4 x 8 edges, 4 gathers in flight
            uint k[4];
            u4v u[4];
#pragma unroll
            for (int j = 0; j < 4; ++j) k[j] = (uint)esrc[i + 8 * j + g];
#pragma unroll
            for (int j = 0; j < 4; ++j) u[j] = z4[k[j] * 8u + (uint)c];
#pragma unroll
            for (int j = 0; j < 4; ++j) {
                f2v t0 = {bf_lo(u[j].x), bf_hi(u[j].x)};
                f2v t1 = {bf_lo(u[j].y), bf_hi(u[j].y)};
                f2v t2 = {bf_lo(u[j].z), bf_hi(u[j].z)};
                f2v t3 = {bf_lo(u[j].w), bf_hi(u[j].w)};
                a0 += t0;
                a1 += t1;
                a2 += t2;
                a3 += t3;
            }
        }
        for (; i < end; i += 8) {
            int idx = i + g;
            u4v uu = {0u, 0u, 0u, 0u};
            if (idx < end) uu = z4[(uint)esrc[idx] * 8u + (uint)c];
            f2v t0 = {bf_lo(uu.x), bf_hi(uu.x)};
            f2v t1 = {bf_lo(uu.y), bf_hi(uu.y)};
            f2v t2 = {bf_lo(uu.z), bf_hi(uu.z)};
            f2v t3 = {bf_lo(uu.w), bf_hi(uu.w)};
            a0 += t0;
            a1 += t1;
            a2 += t2;
            a3 += t3;
        }
#pragma unroll
        for (int d = 8; d <= 32; d <<= 1) {
            a0.x += __shfl_xor(a0.x, d);
            a0.y += __shfl_xor(a0.y, d);
            a1.x += __shfl_xor(a1.x, d);
            a1.y += __shfl_xor(a1.y, d);
            a2.x += __shfl_xor(a2.x, d);
            a2.y += __shfl_xor(a2.y, d);
            a3.x += __shfl_xor(a3.x, d);
            a3.y += __shfl_xor(a3.y, d);
        }
        if (g == 0) {
            u4v self = z4[(uint)v * 8u + (uint)c];
            u4v o = {bf16pack(a0.x + bf_lo(self.x) + cc0.x, a0.y + bf_hi(self.x) + cc0.y),
                     bf16pack(a1.x + bf_lo(self.y) + cc0.z, a1.y + bf_hi(self.y) + cc0.w),
                     bf16pack(a2.x + bf_lo(self.z) + cc1.x, a2.y + bf_hi(self.z) + cc1.y),
                     bf16pack(a3.x + bf_lo(self.w) + cc1.z, a3.y + bf_hi(self.w) + cc1.w)};
            __builtin_nontemporal_store(o, &((u4v*)zn)[(uint)v * 8u + (uint)c]);
        }
    }
}

// Final pass: out = z + A z + 1 c4   (fp32 out)
__global__ __launch_bounds__(256) void agg64_last(const uint* __restrict__ z,
                                                  const int* __restrict__ row_ptr,
                                                  const int* __restrict__ esrc,
                                                  const float* __restrict__ cvec,
                                                  float* __restrict__ out) {
    const u4v* z4 = (const u4v*)z;
    int lane = threadIdx.x & 63;
    int c = lane & 7;
    int g = lane >> 3;
    int wid = (blockIdx.x * blockDim.x + threadIdx.x) >> 6;
    int nw = (gridDim.x * blockDim.x) >> 6;
    f4v cc0 = ((const f4v*)cvec)[2 * c];
    f4v cc1 = ((const f4v*)cvec)[2 * c + 1];
    for (int v = wid; v < N_NODES; v += nw) {
        f2v a0 = {0.f, 0.f}, a1 = {0.f, 0.f}, a2 = {0.f, 0.f}, a3 = {0.f, 0.f};
        int beg = row_ptr[v], end = row_ptr[v + 1];
        int i = beg;
        for (; i + 32 <= end; i += 32) {
            uint k[4];
            u4v u[4];
#pragma unroll
            for (int j = 0; j < 4; ++j) k[j] = (uint)esrc[i + 8 * j + g];
#pragma unroll
            for (int j = 0; j < 4; ++j) u[j] = z4[k[j] * 8u + (uint)c];
#pragma unroll
            for (int j = 0; j < 4; ++j) {
                f2v t0 = {bf_lo(u[j].x), bf_hi(u[j].x)};
                f2v t1 = {bf_lo(u[j].y), bf_hi(u[j].y)};
                f2v t2 = {bf_lo(u[j].z), bf_hi(u[j].z)};
                f2v t3 = {bf_lo(u[j].w), bf_hi(u[j].w)};
                a0 += t0;
                a1 += t1;
                a2 += t2;
                a3 += t3;
            }
        }
        for (; i < end; i += 8) {
            int idx = i + g;
            u4v uu = {0u, 0u, 0u, 0u};
            if (idx < end) uu = z4[(uint)esrc[idx] * 8u + (uint)c];
            f2v t0 = {bf_lo(uu.x), bf_hi(uu.x)};
            f2v t1 = {bf_lo(uu.y), bf_hi(uu.y)};
            f2v t2 = {bf_lo(uu.z), bf_hi(uu.z)};
            f2v t3 = {bf_lo(uu.w), bf_hi(uu.w)};
            a0 += t0;
            a1 += t1;
            a2 += t2;
            a3 += t3;
        }
#pragma unroll
        for (int d = 8; d <= 32; d <<= 1) {
            a0.x += __shfl_xor(a0.x, d);
            a0.y += __shfl_xor(a0.y, d);
            a1.x += __shfl_xor(a1.x, d);
            a1.y += __shfl_xor(a1.y, d);
            a2.x += __shfl_xor(a2.x, d);
            a2.y += __shfl_xor(a2.y, d);
            a3.x += __shfl_xor(a3.x, d);
            a3.y += __shfl_xor(a3.y, d);
        }
        if (g == 0) {
            u4v self = z4[(uint)v * 8u + (uint)c];
            f4v o0 = {a0.x + bf_lo(self.x) + cc0.x, a0.y + bf_hi(self.x) + cc0.y,
                      a1.x + bf_lo(self.y) + cc0.z, a1.y + bf_hi(self.y) + cc0.w};
            f4v o1 = {a2.x + bf_lo(self.z) + cc1.x, a2.y + bf_hi(self.z) + cc1.y,
                      a3.x + bf_lo(self.w) + cc1.z, a3.y + bf_hi(self.w) + cc1.w};
            __builtin_nontemporal_store(o0, &((f4v*)out)[(uint)v * 16u + 2u * (uint)c]);
            __builtin_nontemporal_store(o1, &((f4v*)out)[(uint)v * 16u + 2u * (uint)c + 1u]);
        }
    }
}

// ---------- MFMA GEMM: z0 = h (fp32 [N][128]) @ S0 -> bf16 [N][64] ----------

__global__ __launch_bounds__(256) void mfma_gemm64(const float* __restrict__ x,
                                                   const u4v* __restrict__ Wt,
                                                   uint* __restrict__ y) {
    constexpr int SMEM = 32768 + 64 * 256;  // A (32K) + B (16K); epilogue reuses A
    __shared__ char raw[SMEM];
    u4v* Asm = (u4v*)raw;                  // [128][16] swizzled
    u4v* Bsm = (u4v*)(raw + 32768);        // [64][16] swizzled
    float* Cst = (float*)raw;              // [128][64] fp32 epilogue overlay (32K)
    int tid = threadIdx.x;
    int m0 = blockIdx.x * 128;

#pragma unroll
    for (int i = 0; i < 8; ++i) {
        int idx = tid + i * 256;
        int r = idx >> 4, c16 = idx & 15;
        int m = m0 + r;
        if (m >= N_NODES) m = N_NODES - 1;
        const float* src = &x[(size_t)m * 128 + c16 * 8];
        f4v v0 = *(const f4v*)src;
        f4v v1 = *(const f4v*)(src + 4);
        u4v o = {bf16pack(v0.x, v0.y), bf16pack(v0.z, v0.w),
                 bf16pack(v1.x, v1.y), bf16pack(v1.z, v1.w)};
        Asm[r * 16 + (c16 ^ (r & 7))] = o;
    }
#pragma unroll
    for (int i = 0; i < 4; ++i) Bsm[tid + i * 256] = Wt[tid + i * 256];
    __syncthreads();

    int lane = tid & 63;
    int w = tid >> 6;
    int n0w = w * 16;
    int lhi = lane >> 4, llo = lane & 15;
    f32x4 acc[8];
#pragma unroll
    for (int i = 0; i < 8; ++i) acc[i] = (f32x4){0.f, 0.f, 0.f, 0.f};

#pragma unroll
    for (int ks = 0; ks < 4; ++ks) {
        int cb = ks * 4 + lhi;
        int col = n0w + llo;
        u4v tb = Bsm[col * 16 + (cb ^ (col & 7))];
        s8v bfr = *(s8v*)&tb;
#pragma unroll
        for (int i = 0; i < 8; ++i) {
            int row = i * 16 + llo;
            u4v t = Asm[row * 16 + (cb ^ (row & 7))];
            s8v aa = *(s8v*)&t;
            acc[i] = __builtin_amdgcn_mfma_f32_16x16x32_bf16(aa, bfr, acc[i], 0, 0, 0);
        }
    }
    __syncthreads();
#pragma unroll
    for (int i = 0; i < 8; ++i)
#pragma unroll
        for (int r = 0; r < 4; ++r)
            Cst[(i * 16 + lhi * 4 + r) * 64 + n0w + llo] = acc[i][r];
    __syncthreads();
#pragma unroll
    for (int i = 0; i < 16; ++i) {
        int idx = tid + i * 256;
        int m = idx >> 5, np = idx & 31;
        if (m0 + m < N_NODES)
            y[(size_t)(m0 + m) * 32 + np] =
                bf16pack(Cst[m * 64 + 2 * np], Cst[m * 64 + 2 * np + 1]);
    }
}

extern "C" void kernel_launch(void* const* d_in, const int* in_sizes, int n_in,
                              void* d_out, int out_size, void* d_ws, size_t ws_size,
                              hipStream_t stream) {
    const float* h_in = (const float*)d_in[0];
    const void* edges = d_in[1];
    const float* W[5] = {(const float*)d_in[2], (const float*)d_in[4], (const float*)d_in[6],
                         (const float*)d_in[8], (const float*)d_in[10]};
    const float* B[5] = {(const float*)d_in[3], (const float*)d_in[5], (const float*)d_in[7],
                         (const float*)d_in[9], (const float*)d_in[11]};

    size_t off = 0;
    auto alloc = [&](size_t bytes) {
        void* p = (char*)d_ws + off;
        off = (off + bytes + 255) & ~(size_t)255;
        return p;
    };
    int* esorted = (int*)alloc((size_t)N_EDGES * 4);            // 12.8 MB
    int* row_ptr = (int*)alloc((size_t)(N_NODES + 1) * 4);
    int* hist2 = (int*)alloc((size_t)NCHUNKS * NB * 4);         // 2.45 MB [b][c]
    int* base2 = (int*)alloc((size_t)NCHUNKS * NB * 4);         // 2.45 MB [c][b]
    int* bcount = (int*)alloc((size_t)NB * 4);
    int* boff = (int*)alloc((size_t)(NB + 1) * 4);
    int* flag = (int*)alloc(256);
    float* Sa = (float*)alloc(128 * 64 * 4);                    // 32 KB ping
    float* Sb = (float*)alloc(128 * 64 * 4);                    // 32 KB pong
    float* c_all = (float*)alloc(5 * 64 * 4);
    u4v* Wt_z = (u4v*)alloc((size_t)64 * 16 * 16);              // 16 KB
    uint* zA = (uint*)alloc((size_t)N_NODES * 32 * 4);          // 12.8 MB
    uint* zB = (uint*)alloc((size_t)N_NODES * 32 * 4);          // 12.8 MB
    uint* tmp = (uint*)alloc((size_t)N_EDGES * 4);              // 12.8 MB (build only)

    // ---- build CSR ----
    detect_fmt<<<1, 64, 0, stream>>>((const uint*)edges, flag, row_ptr);
    (void)hipMemsetAsync(bcount, 0, (size_t)NB * 4, stream);
    part_hist<<<NCHUNKS, 256, 0, stream>>>(edges, flag, hist2, bcount);
    scan_kernel<<<1, 1024, 0, stream>>>(bcount, boff, NB);
    chunk_scan<<<NB, 1024, 0, stream>>>(hist2, boff, base2);
    part_scatter<<<NCHUNKS_S, 1024, 0, stream>>>(edges, flag, base2, tmp);
    bucket_finalize<<<NB, 256, 0, stream>>>(tmp, boff, row_ptr, esorted);

    // ---- collapse prep: S_l chain + c_l = b_l^T S_{l+1} ----
    matstage<<<33, 256, 0, stream>>>(W[3], B[3], W[4], Sa, c_all + 3 * 64);  // S3, c3
    matstage<<<33, 256, 0, stream>>>(W[2], B[2], Sa, Sb, c_all + 2 * 64);    // S2, c2
    matstage<<<33, 256, 0, stream>>>(W[1], B[1], Sb, Sa, c_all + 1 * 64);    // S1, c1
    matstage<<<33, 256, 0, stream>>>(W[0], B[0], Sa, Sb, c_all + 0 * 64);    // S0, c0
    prep_z<<<4, 256, 0, stream>>>(Sb, B[4], Wt_z, c_all);                    // Wt_z, c4

    // ---- z0 = h @ S0; y_{l+1} = (I+A) y_l + c_l (x5, last writes fp32 out) ----
    mfma_gemm64<<<(N_NODES + 127) / 128, 256, 0, stream>>>(h_in, Wt_z, zA);
    agg64_step<<<2048, 256, 0, stream>>>(zA, row_ptr, esorted, c_all + 0 * 64, zB);
    agg64_step<<<2048, 256, 0, stream>>>(zB, row_ptr, esorted, c_all + 1 * 64, zA);
    agg64_step<<<2048, 256, 0, stream>>>(zA, row_ptr, esorted, c_all + 2 * 64, zB);
    agg64_step<<<2048, 256, 0, stream>>>(zB, row_ptr, esorted, c_all + 3 * 64, zA);
    agg64_last<<<2048, 256, 0, stream>>>(zA, row_ptr, esorted, c_all + 4 * 64,
                                         (float*)d_out);
}

// Round 23
// 406.838 us; speedup vs baseline: 1.1978x; 1.0399x over previous
//
#include <hip/hip_runtime.h>

#define N_NODES 100000
#define N_EDGES 3200000
#define NB 782          // dst buckets of 128 nodes: ceil(100000/128)
#define BCAP 5120       // max edges per bucket (avg 4096, 16 sigma guard)
#define CHUNK_EDGES 4096
#define NCHUNKS ((N_EDGES + CHUNK_EDGES - 1) / CHUNK_EDGES)  // 782 (hist granularity)
#define CHUNK_S 16384
#define SC_FACTOR (CHUNK_S / CHUNK_EDGES)                    // 4
#define NCHUNKS_S ((N_EDGES + CHUNK_S - 1) / CHUNK_S)        // 196 (scatter granularity)

typedef unsigned int uint;
typedef __attribute__((ext_vector_type(2))) uint u2v;
typedef __attribute__((ext_vector_type(4))) uint u4v;
typedef __attribute__((ext_vector_type(2))) float f2v;
typedef __attribute__((ext_vector_type(4))) float f4v;
typedef __attribute__((ext_vector_type(8))) short s8v;   // 8 bf16 (4 VGPRs)
typedef __attribute__((ext_vector_type(4))) float f32x4; // mfma acc

// ---------- CSR build: deterministic two-pass bucket partition ----------

__global__ void detect_fmt(const uint* __restrict__ e, int* __restrict__ flag,
                           int* __restrict__ row_ptr) {
    if (threadIdx.x == 0) {
        *flag = (e[1] == 0u && e[3] == 0u && e[5] == 0u && e[7] == 0u) ? 1 : 0;
        row_ptr[N_NODES] = N_EDGES;
    }
}

__device__ __forceinline__ int load_idx(const void* edges, int fmt, long long i) {
    return fmt ? (int)((const long long*)edges)[i] : ((const int*)edges)[i];
}

// hist2 layout: [bucket][chunk] so chunk_scan reads coalesced.
__global__ __launch_bounds__(256) void part_hist(const void* __restrict__ edges,
                                                 const int* __restrict__ flag,
                                                 int* __restrict__ hist2,
                                                 int* __restrict__ bcount) {
    __shared__ int cnt[NB];
    for (int i = threadIdx.x; i < NB; i += 256) cnt[i] = 0;
    __syncthreads();
    int fmt = *flag;
    int c = blockIdx.x;
    int beg = c * CHUNK_EDGES, end = min(beg + CHUNK_EDGES, N_EDGES);
    for (int i = beg + threadIdx.x; i < end; i += 256) {
        int dst = load_idx(edges, fmt, (long long)N_EDGES + i);
        atomicAdd(&cnt[dst >> 7], 1);
    }
    __syncthreads();
    for (int i = threadIdx.x; i < NB; i += 256) {
        hist2[i * NCHUNKS + c] = cnt[i];
        if (cnt[i]) atomicAdd(&bcount[i], cnt[i]);
    }
}

__global__ void scan_kernel(const int* __restrict__ count, int* __restrict__ off_out, int n) {
    __shared__ int sums[1024];
    int t = threadIdx.x;
    int chunk = (n + 1023) >> 10;
    int beg = t * chunk;
    int end = min(beg + chunk, n);
    int s = 0;
    for (int i = beg; i < end; ++i) s += count[i];
    sums[t] = s;
    __syncthreads();
    int val = s;
    for (int off = 1; off < 1024; off <<= 1) {
        int other = (t >= off) ? sums[t - off] : 0;
        __syncthreads();
        val += other;
        sums[t] = val;
        __syncthreads();
    }
    int run = val - s;
    for (int i = beg; i < end; ++i) {
        off_out[i] = run;
        run += count[i];
    }
    if (end >= n) off_out[n] = run;
}

// One block per bucket (1024 threads): exclusive scan over NCHUNKS (782) chunks.
__global__ __launch_bounds__(1024) void chunk_scan(const int* __restrict__ hist2,
                                                   const int* __restrict__ boff,
                                                   int* __restrict__ base2) {
    __shared__ int s[1024];
    int b = blockIdx.x;
    int t = threadIdx.x;
    int v = (t < NCHUNKS) ? hist2[b * NCHUNKS + t] : 0;
    s[t] = v;
    __syncthreads();
    int val = v;
    for (int off = 1; off < 1024; off <<= 1) {
        int o = (t >= off) ? s[t - off] : 0;
        __syncthreads();
        val += o;
        s[t] = val;
        __syncthreads();
    }
    if (t < NCHUNKS) base2[t * NB + b] = boff[b] + val - v;
}

// Scatter in coarse chunks (SC_FACTOR hist chunks each). 196 blocks -> ~2x CU
// utilization vs 98; streams ~21 edges (~1.7 lines) keep write amp moderate.
__global__ __launch_bounds__(1024) void part_scatter(const void* __restrict__ edges,
                                                     const int* __restrict__ flag,
                                                     const int* __restrict__ base2,
                                                     uint* __restrict__ tmp) {
    __shared__ int cur[NB];
    int c = blockIdx.x;
    for (int i = threadIdx.x; i < NB; i += 1024) cur[i] = base2[(c * SC_FACTOR) * NB + i];
    __syncthreads();
    int fmt = *flag;
    int beg = c * CHUNK_S, end = min(beg + CHUNK_S, N_EDGES);
    for (int i = beg + (int)threadIdx.x; i < end; i += 1024) {
        int src = load_idx(edges, fmt, i);
        int dst = load_idx(edges, fmt, (long long)N_EDGES + i);
        int b = dst >> 7;
        int pos = atomicAdd(&cur[b], 1);
        tmp[pos] = ((uint)(dst & 127) << 17) | (uint)src;  // src < 2^17
    }
}

__global__ __launch_bounds__(256) void bucket_finalize(const uint* __restrict__ tmp,
                                                       const int* __restrict__ boff,
                                                       int* __restrict__ row_ptr,
                                                       int* __restrict__ esorted) {
    __shared__ uint s1[BCAP];
    __shared__ int s2[BCAP];
    __shared__ int cnt[128], pref[128], cur[128];
    int b = blockIdx.x;
    int beg = boff[b];
    int n = boff[b + 1] - beg;
    if (n > BCAP) n = BCAP;
    int t = threadIdx.x;
    if (t < 128) cnt[t] = 0;
    __syncthreads();
    for (int e = t; e < n; e += 256) {
        uint k = tmp[beg + e];
        s1[e] = k;
        atomicAdd(&cnt[k >> 17], 1);
    }
    __syncthreads();
    if (t < 128) pref[t] = cnt[t];
    __syncthreads();
    for (int off = 1; off < 128; off <<= 1) {
        int v = (t < 128 && t >= off) ? pref[t - off] : 0;
        __syncthreads();
        if (t < 128) pref[t] += v;
        __syncthreads();
    }
    if (t < 128) {
        int ex = pref[t] - cnt[t];
        cur[t] = ex;
        int node = b * 128 + t;
        if (node < N_NODES) row_ptr[node] = beg + ex;
    }
    __syncthreads();
    for (int e = t; e < n; e += 256) {
        uint k = s1[e];
        int p = atomicAdd(&cur[k >> 17], 1);
        s2[p] = (int)(k & 0x1FFFF);
    }
    __syncthreads();
    for (int e = t; e < n; e += 256) esorted[beg + e] = s2[e];
}

// ---------- bf16 helpers ----------

__device__ __forceinline__ uint bf16pack(float a, float b) {
    uint ua = __float_as_uint(a);
    ua = (ua + 0x7FFFu + ((ua >> 16) & 1u)) >> 16;  // RNE
    uint ub = __float_as_uint(b);
    ub = (ub + 0x7FFFu + ((ub >> 16) & 1u)) >> 16;
    return ua | (ub << 16);
}
__device__ __forceinline__ float bf_lo(uint u) { return __uint_as_float(u << 16); }
__device__ __forceinline__ float bf_hi(uint u) { return __uint_as_float(u & 0xFFFF0000u); }

// ---------- linear collapse prep (parallel stages) ----------
// y_{l+1} = (I+A) y_l + 1 c_l with y_0 = h S0, out = y_5.
// S_l = W_l...W_4 ; c_l = b_l^T S_{l+1}.

__global__ __launch_bounds__(256) void matstage(const float* __restrict__ Wl,
                                                const float* __restrict__ bl,
                                                const float* __restrict__ Sin,
                                                float* __restrict__ Sout,
                                                float* __restrict__ cout) {
    __shared__ float S[128 * 64];  // 32 KB
    int tid = threadIdx.x;
    int b = blockIdx.x;
    for (int i = tid; i < 128 * 16; i += 256) ((f4v*)S)[i] = ((const f4v*)Sin)[i];
    __syncthreads();
    if (b < 32) {
        int rr = tid >> 6;
        int c = tid & 63;
        int r = b * 4 + rr;
        const float* wrow = &Wl[r * 128];
        float s = 0.f;
#pragma unroll 8
        for (int k = 0; k < 128; ++k) s += wrow[k] * S[k * 64 + c];
        Sout[r * 64 + c] = s;
    } else if (tid < 64) {
        float s = 0.f;
        for (int k = 0; k < 128; ++k) s += bl[k] * S[k * 64 + tid];
        cout[tid] = s;
    }
}

// Transpose S0 (fp32 [128][64]) -> bf16 [n][c16] u4v, XOR-swizzled; also c4 = b4.
__global__ __launch_bounds__(256) void prep_z(const float* __restrict__ S0,
                                              const float* __restrict__ b4,
                                              u4v* __restrict__ Wt,
                                              float* __restrict__ c_all) {
    int idx = blockIdx.x * 256 + threadIdx.x;  // n*16 + c16, 1024 total
    if (blockIdx.x == 0 && threadIdx.x < 64) c_all[4 * 64 + threadIdx.x] = b4[threadIdx.x];
    if (idx >= 64 * 16) return;
    int n = idx >> 4, c16 = idx & 15;
    u4v o;
#pragma unroll
    for (int q = 0; q < 4; ++q)
        o[q] = bf16pack(S0[(size_t)(c16 * 8 + 2 * q) * 64 + n],
                        S0[(size_t)(c16 * 8 + 2 * q + 1) * 64 + n]);
    Wt[n * 16 + (c16 ^ (n & 7))] = o;
}

// ---------- 64-dim aggregation pass: zn = z + A z + 1 c  (bf16 -> bf16) ----------
// 8 edges/wave-instr: 8-lane groups, lane loads u4v (16B) -> one
// global_load_dwordx4 covers 8 full 128B rows. 3-level shfl_xor merge.

__global__ __launch_bounds__(256) void agg64_step(const uint* __restrict__ z,
                                                  const int* __restrict__ row_ptr,
                                                  const int* __restrict__ esrc,
                                                  const float* __restrict__ cvec,
                                                  uint* __restrict__ zn) {
    const u4v* z4 = (const u4v*)z;
    int lane = threadIdx.x & 63;
    int c = lane & 7;    // u4v col: dims 8c..8c+7
    int g = lane >> 3;   // edge group 0..7
    int wid = (blockIdx.x * blockDim.x + threadIdx.x) >> 6;
    int nw = (gridDim.x * blockDim.x) >> 6;
    f4v cc0 = ((const f4v*)cvec)[2 * c];
    f4v cc1 = ((const f4v*)cvec)[2 * c + 1];
    for (int v = wid; v < N_NODES; v += nw) {
        f2v a0 = {0.f, 0.f}, a1 = {0.f, 0.f}, a2 = {0.f, 0.f}, a3 = {0.f, 0.f};
        int beg = row_ptr[v], end = row_ptr[v + 1];
        int i = beg;
        for (; i + 32 <= end; i += 32) {  // 4 x 8 edges, 4 gathers in flight
            uint k[4];
            u4v u[4];
#pragma unroll
            for (int j = 0; j < 4; ++j) k[j] = (uint)esrc[i + 8 * j + g];
#pragma unroll
            for (int j = 0; j < 4; ++j) u[j] = z4[k[j] * 8u + (uint)c];
#pragma unroll
            for (int j = 0; j < 4; ++j) {
                f2v t0 = {bf_lo(u[j].x), bf_hi(u[j].x)};
                f2v t1 = {bf_lo(u[j].y), bf_hi(u[j].y)};
                f2v t2 = {bf_lo(u[j].z), bf_hi(u[j].z)};
                f2v t3 = {bf_lo(u[j].w), bf_hi(u[j].w)};
                a0 += t0;
                a1 += t1;
                a2 += t2;
                a3 += t3;
            }
        }
        for (; i < end; i += 8) {
            int idx = i + g;
            u4v uu = {0u, 0u, 0u, 0u};
            if (idx < end) uu = z4[(uint)esrc[idx] * 8u + (uint)c];
            f2v t0 = {bf_lo(uu.x), bf_hi(uu.x)};
            f2v t1 = {bf_lo(uu.y), bf_hi(uu.y)};
            f2v t2 = {bf_lo(uu.z), bf_hi(uu.z)};
            f2v t3 = {bf_lo(uu.w), bf_hi(uu.w)};
            a0 += t0;
            a1 += t1;
            a2 += t2;
            a3 += t3;
        }
#pragma unroll
        for (int d = 8; d <= 32; d <<= 1) {
            a0.x += __shfl_xor(a0.x, d);
            a0.y += __shfl_xor(a0.y, d);
            a1.x += __shfl_xor(a1.x, d);
            a1.y += __shfl_xor(a1.y, d);
            a2.x += __shfl_xor(a2.x, d);
            a2.y += __shfl_xor(a2.y, d);
            a3.x += __shfl_xor(a3.x, d);
            a3.y += __shfl_xor(a3.y, d);
        }
        if (g == 0) {
            u4v self = z4[(uint)v * 8u + (uint)c];
            u4v o = {bf16pack(a0.x + bf_lo(self.x) + cc0.x, a0.y + bf_hi(self.x) + cc0.y),
                     bf16pack(a1.x + bf_lo(self.y) + cc0.z, a1.y + bf_hi(self.y) + cc0.w),
                     bf16pack(a2.x + bf_lo(self.z) + cc1.x, a2.y + bf_hi(self.z) + cc1.y),
                     bf16pack(a3.x + bf_lo(self.w) + cc1.z, a3.y + bf_hi(self.w) + cc1.w)};
            __builtin_nontemporal_store(o, &((u4v*)zn)[(uint)v * 8u + (uint)c]);
        }
    }
}

// Final pass: out = z + A z + 1 c4   (fp32 out)
__global__ __launch_bounds__(256) void agg64_last(const uint* __restrict__ z,
                                                  const int* __restrict__ row_ptr,
                                                  const int* __restrict__ esrc,
                                                  const float* __restrict__ cvec,
                                                  float* __restrict__ out) {
    const u4v* z4 = (const u4v*)z;
    int lane = threadIdx.x & 63;
    int c = lane & 7;
    int g = lane >> 3;
    int wid = (blockIdx.x * blockDim.x + threadIdx.x) >> 6;
    int nw = (gridDim.x * blockDim.x) >> 6;
    f4v cc0 = ((const f4v*)cvec)[2 * c];
    f4v cc1 = ((const f4v*)cvec)[2 * c + 1];
    for (int v = wid; v < N_NODES; v += nw) {
        f2v a0 = {0.f, 0.f}, a1 = {0.f, 0.f}, a2 = {0.f, 0.f}, a3 = {0.f, 0.f};
        int beg = row_ptr[v], end = row_ptr[v + 1];
        int i = beg;
        for (; i + 32 <= end; i += 32) {
            uint k[4];
            u4v u[4];
#pragma unroll
            for (int j = 0; j < 4; ++j) k[j] = (uint)esrc[i + 8 * j + g];
#pragma unroll
            for (int j = 0; j < 4; ++j) u[j] = z4[k[j] * 8u + (uint)c];
#pragma unroll
            for (int j = 0; j < 4; ++j) {
                f2v t0 = {bf_lo(u[j].x), bf_hi(u[j].x)};
                f2v t1 = {bf_lo(u[j].y), bf_hi(u[j].y)};
                f2v t2 = {bf_lo(u[j].z), bf_hi(u[j].z)};
                f2v t3 = {bf_lo(u[j].w), bf_hi(u[j].w)};
                a0 += t0;
                a1 += t1;
                a2 += t2;
                a3 += t3;
            }
        }
        for (; i < end; i += 8) {
            int idx = i + g;
            u4v uu = {0u, 0u, 0u, 0u};
            if (idx < end) uu = z4[(uint)esrc[idx] * 8u + (uint)c];
            f2v t0 = {bf_lo(uu.x), bf_hi(uu.x)};
            f2v t1 = {bf_lo(uu.y), bf_hi(uu.y)};
            f2v t2 = {bf_lo(uu.z), bf_hi(uu.z)};
            f2v t3 = {bf_lo(uu.w), bf_hi(uu.w)};
            a0 += t0;
            a1 += t1;
            a2 += t2;
            a3 += t3;
        }
#pragma unroll
        for (int d = 8; d <= 32; d <<= 1) {
            a0.x += __shfl_xor(a0.x, d);
            a0.y += __shfl_xor(a0.y, d);
            a1.x += __shfl_xor(a1.x, d);
            a1.y += __shfl_xor(a1.y, d);
            a2.x += __shfl_xor(a2.x, d);
            a2.y += __shfl_xor(a2.y, d);
            a3.x += __shfl_xor(a3.x, d);
            a3.y += __shfl_xor(a3.y, d);
        }
        if (g == 0) {
            u4v self = z4[(uint)v * 8u + (uint)c];
            f4v o0 = {a0.x + bf_lo(self.x) + cc0.x, a0.y + bf_hi(self.x) + cc0.y,
                      a1.x + bf_lo(self.y) + cc0.z, a1.y + bf_hi(self.y) + cc0.w};
            f4v o1 = {a2.x + bf_lo(self.z) + cc1.x, a2.y + bf_hi(self.z) + cc1.y,
                      a3.x + bf_lo(self.w) + cc1.z, a3.y + bf_hi(self.w) + cc1.w};
            __builtin_nontemporal_store(o0, &((f4v*)out)[(uint)v * 16u + 2u * (uint)c]);
            __builtin_nontemporal_store(o1, &((f4v*)out)[(uint)v * 16u + 2u * (uint)c + 1u]);
        }
    }
}

// ---------- MFMA GEMM: z0 = h (fp32 [N][128]) @ S0 -> bf16 [N][64] ----------

__global__ __launch_bounds__(256) void mfma_gemm64(const float* __restrict__ x,
                                                   const u4v* __restrict__ Wt,
                                                   uint* __restrict__ y) {
    constexpr int SMEM = 32768 + 64 * 256;  // A (32K) + B (16K); epilogue reuses A
    __shared__ char raw[SMEM];
    u4v* Asm = (u4v*)raw;                  // [128][16] swizzled
    u4v* Bsm = (u4v*)(raw + 32768);        // [64][16] swizzled
    float* Cst = (float*)raw;              // [128][64] fp32 epilogue overlay (32K)
    int tid = threadIdx.x;
    int m0 = blockIdx.x * 128;

#pragma unroll
    for (int i = 0; i < 8; ++i) {
        int idx = tid + i * 256;
        int r = idx >> 4, c16 = idx & 15;
        int m = m0 + r;
        if (m >= N_NODES) m = N_NODES - 1;
        const float* src = &x[(size_t)m * 128 + c16 * 8];
        f4v v0 = *(const f4v*)src;
        f4v v1 = *(const f4v*)(src + 4);
        u4v o = {bf16pack(v0.x, v0.y), bf16pack(v0.z, v0.w),
                 bf16pack(v1.x, v1.y), bf16pack(v1.z, v1.w)};
        Asm[r * 16 + (c16 ^ (r & 7))] = o;
    }
#pragma unroll
    for (int i = 0; i < 4; ++i) Bsm[tid + i * 256] = Wt[tid + i * 256];
    __syncthreads();

    int lane = tid & 63;
    int w = tid >> 6;
    int n0w = w * 16;
    int lhi = lane >> 4, llo = lane & 15;
    f32x4 acc[8];
#pragma unroll
    for (int i = 0; i < 8; ++i) acc[i] = (f32x4){0.f, 0.f, 0.f, 0.f};

#pragma unroll
    for (int ks = 0; ks < 4; ++ks) {
        int cb = ks * 4 + lhi;
        int col = n0w + llo;
        u4v tb = Bsm[col * 16 + (cb ^ (col & 7))];
        s8v bfr = *(s8v*)&tb;
#pragma unroll
        for (int i = 0; i < 8; ++i) {
            int row = i * 16 + llo;
            u4v t = Asm[row * 16 + (cb ^ (row & 7))];
            s8v aa = *(s8v*)&t;
            acc[i] = __builtin_amdgcn_mfma_f32_16x16x32_bf16(aa, bfr, acc[i], 0, 0, 0);
        }
    }
    __syncthreads();
#pragma unroll
    for (int i = 0; i < 8; ++i)
#pragma unroll
        for (int r = 0; r < 4; ++r)
            Cst[(i * 16 + lhi * 4 + r) * 64 + n0w + llo] = acc[i][r];
    __syncthreads();
#pragma unroll
    for (int i = 0; i < 16; ++i) {
        int idx = tid + i * 256;
        int m = idx >> 5, np = idx & 31;
        if (m0 + m < N_NODES)
            y[(size_t)(m0 + m) * 32 + np] =
                bf16pack(Cst[m * 64 + 2 * np], Cst[m * 64 + 2 * np + 1]);
    }
}

extern "C" void kernel_launch(void* const* d_in, const int* in_sizes, int n_in,
                              void* d_out, int out_size, void* d_ws, size_t ws_size,
                              hipStream_t stream) {
    const float* h_in = (const float*)d_in[0];
    const void* edges = d_in[1];
    const float* W[5] = {(const float*)d_in[2], (const float*)d_in[4], (const float*)d_in[6],
                         (const float*)d_in[8], (const float*)d_in[10]};
    const float* B[5] = {(const float*)d_in[3], (const float*)d_in[5], (const float*)d_in[7],
                         (const float*)d_in[9], (const float*)d_in[11]};

    size_t off = 0;
    auto alloc = [&](size_t bytes) {
        void* p = (char*)d_ws + off;
        off = (off + bytes + 255) & ~(size_t)255;
        return p;
    };
    int* esorted = (int*)alloc((size_t)N_EDGES * 4);            // 12.8 MB
    int* row_ptr = (int*)alloc((size_t)(N_NODES + 1) * 4);
    int* hist2 = (int*)alloc((size_t)NCHUNKS * NB * 4);         // 2.45 MB [b][c]
    int* base2 = (int*)alloc((size_t)NCHUNKS * NB * 4);         // 2.45 MB [c][b]
    int* bcount = (int*)alloc((size_t)NB * 4);
    int* boff = (int*)alloc((size_t)(NB + 1) * 4);
    int* flag = (int*)alloc(256);
    float* Sa = (float*)alloc(128 * 64 * 4);                    // 32 KB ping
    float* Sb = (float*)alloc(128 * 64 * 4);                    // 32 KB pong
    float* c_all = (float*)alloc(5 * 64 * 4);
    u4v* Wt_z = (u4v*)alloc((size_t)64 * 16 * 16);              // 16 KB
    uint* zA = (uint*)alloc((size_t)N_NODES * 32 * 4);          // 12.8 MB
    uint* zB = (uint*)alloc((size_t)N_NODES * 32 * 4);          // 12.8 MB
    uint* tmp = (uint*)alloc((size_t)N_EDGES * 4);              // 12.8 MB (build only)

    // ---- build CSR ----
    detect_fmt<<<1, 64, 0, stream>>>((const uint*)edges, flag, row_ptr);
    (void)hipMemsetAsync(bcount, 0, (size_t)NB * 4, stream);
    part_hist<<<NCHUNKS, 256, 0, stream>>>(edges, flag, hist2, bcount);
    scan_kernel<<<1, 1024, 0, stream>>>(bcount, boff, NB);
    chunk_scan<<<NB, 1024, 0, stream>>>(hist2, boff, base2);
    part_scatter<<<NCHUNKS_S, 1024, 0, stream>>>(edges, flag, base2, tmp);
    bucket_finalize<<<NB, 256, 0, stream>>>(tmp, boff, row_ptr, esorted);

    // ---- collapse prep: S_l chain + c_l = b_l^T S_{l+1} ----
    matstage<<<33, 256, 0, stream>>>(W[3], B[3], W[4], Sa, c_all + 3 * 64);  // S3, c3
    matstage<<<33, 256, 0, stream>>>(W[2], B[2], Sa, Sb, c_all + 2 * 64);    // S2, c2
    matstage<<<33, 256, 0, stream>>>(W[1], B[1], Sb, Sa, c_all + 1 * 64);    // S1, c1
    matstage<<<33, 256, 0, stream>>>(W[0], B[0], Sa, Sb, c_all + 0 * 64);    // S0, c0
    prep_z<<<4, 256, 0, stream>>>(Sb, B[4], Wt_z, c_all);                    // Wt_z, c4

    // ---- z0 = h @ S0; y_{l+1} = (I+A) y_l + c_l (x5, last writes fp32 out) ----
    mfma_gemm64<<<(N_NODES + 127) / 128, 256, 0, stream>>>(h_in, Wt_z, zA);
    agg64_step<<<2048, 256, 0, stream>>>(zA, row_ptr, esorted, c_all + 0 * 64, zB);
    agg64_step<<<2048, 256, 0, stream>>>(zB, row_ptr, esorted, c_all + 1 * 64, zA);
    agg64_step<<<2048, 256, 0, stream>>>(zA, row_ptr, esorted, c_all + 2 * 64, zB);
    agg64_step<<<2048, 256, 0, stream>>>(zB, row_ptr, esorted, c_all + 3 * 64, zA);
    agg64_last<<<2048, 256, 0, stream>>>(zA, row_ptr, esorted, c_all + 4 * 64,
                                         (float*)d_out);
}